// Round 6
// baseline (666.184 us; speedup 1.0000x reference)
//
#include <hip/hip_runtime.h>
#include <hip/hip_bf16.h>
#include <hip/hip_fp16.h>
#include <cstdint>

// ---------------------------------------------------------------------------
// SplineNet forward on gfx950 — gather formulation, fp16 Y, int2 edge meta.
//   ygemm:  Y[n, k*Cout+ch] = x[n] @ W[k]   (register-tiled 8x4, grid over kk)
//   gather: agg[n,ch] = sum_e sum_s basis_s(e) * Y[src_e, k_s, ch]
//           wave-per-node; quarter q = spline slot; readlane edge broadcast;
//           batch-4 edge loads; fused finalize epilogue when single-pass.
//   head:   pool + gated MLP + log_softmax.
// ---------------------------------------------------------------------------

struct H4 { __half2 a, b; };

__device__ __forceinline__ int lowb(const int* __restrict__ a, int n, int v) {
  int lo = 0, hi = n;
  while (lo < hi) { int m = (lo + hi) >> 1; if (a[m] < v) lo = m + 1; else hi = m; }
  return lo;
}

__global__ void hist_kernel(const int* __restrict__ dst, int E, int* __restrict__ deg) {
  int e = blockIdx.x * 256 + threadIdx.x;
  if (e < E) atomicAdd(&deg[dst[e]], 1);
}

__global__ __launch_bounds__(1024) void scan_block_kernel(
    const int* __restrict__ deg, int n, int* __restrict__ offs, int* __restrict__ bsums) {
  __shared__ int wsum[16];
  int t = threadIdx.x;
  int gi = blockIdx.x * 1024 + t;
  int v = (gi < n) ? deg[gi] : 0;
  int lane = t & 63, w = t >> 6;
  int x = v;
  #pragma unroll
  for (int d = 1; d < 64; d <<= 1) { int y = __shfl_up(x, d, 64); if (lane >= d) x += y; }
  if (lane == 63) wsum[w] = x;
  __syncthreads();
  if (w == 0) {
    int s = (lane < 16) ? wsum[lane] : 0;
    #pragma unroll
    for (int d = 1; d < 16; d <<= 1) { int y = __shfl_up(s, d, 64); if (lane >= d) s += y; }
    if (lane < 16) wsum[lane] = s;
  }
  __syncthreads();
  int add = (w > 0) ? wsum[w - 1] : 0;
  x += add;
  if (gi < n) offs[gi + 1] = x;
  if (t == 1023) bsums[blockIdx.x] = x;
}

__global__ __launch_bounds__(64) void scan_bsums_kernel(
    const int* __restrict__ bsums, int nb, int* __restrict__ boff) {
  int l = threadIdx.x;
  int v = (l < nb) ? bsums[l] : 0;
  int x = v;
  #pragma unroll
  for (int d = 1; d < 64; d <<= 1) { int y = __shfl_up(x, d, 64); if (l >= d) x += y; }
  if (l < nb) boff[l] = x - v;
}

__global__ void scan_add_kernel(int* __restrict__ offs, const int* __restrict__ boff, int n) {
  int i = blockIdx.x * 256 + threadIdx.x;
  if (i < n) offs[i + 1] += boff[i >> 10];
  if (i == 0) offs[0] = 0;
}

// CSR scatter + packed spline metadata {src, k0|i10<<5|f0q<<7|f1q<<19}.
__global__ void scatter_kernel(const int* __restrict__ src, const int* __restrict__ dst,
                               const float2* __restrict__ attr, int E,
                               const int* __restrict__ offs, int* __restrict__ cursor,
                               int2* __restrict__ emeta) {
  int e = blockIdx.x * 256 + threadIdx.x;
  if (e < E) {
    float2 a = attr[e];
    float v0 = a.x * 4.f, v1 = a.y * 4.f;
    int i00 = min((int)v0, 3);
    int i10 = min((int)v1, 3);
    float f0 = v0 - (float)i00;             // clamp trick: boundary exact
    float f1 = v1 - (float)i10;
    int f0q = (int)(f0 * 4095.f + 0.5f);
    int f1q = (int)(f1 * 4095.f + 0.5f);
    int yw = (i10 * 5 + i00) | (i10 << 5) | (f0q << 7) | (f1q << 19);
    int d = dst[e];
    int p = offs[d] + atomicAdd(&cursor[d], 1);
    emeta[p] = make_int2(src[e], yw);
  }
}

// Register-tiled ygemm: block = 128 rows x COUT cols for ONE kk (grid.y).
// Thread computes 8 rows x 4 cols; 12 LDS floats per 32 FMA.
template <int COUT>
__global__ __launch_bounds__(COUT * 4) void ygemm_kernel(
    const float* __restrict__ X, const float* __restrict__ Wsrc,
    __half* __restrict__ Y, int N, int kFirst, int strideY) {
  constexpr int THREADS = COUT * 4;
  __shared__ float Xs[128][33];
  __shared__ float Ws[32 * COUT];
  const int t = threadIdx.x;
  const int kk = blockIdx.y;
  const int n0 = blockIdx.x * 128;
  constexpr int XF4 = 1024 / THREADS;       // float4s per thread (X staging)
  #pragma unroll
  for (int q = 0; q < XF4; ++q) {
    int idx = t + q * THREADS;              // 0..1023
    int row = idx >> 3, c4 = (idx & 7) * 4;
    float4 v = *(const float4*)&X[(size_t)min(n0 + row, N - 1) * 32 + c4];
    Xs[row][c4 + 0] = v.x; Xs[row][c4 + 1] = v.y;
    Xs[row][c4 + 2] = v.z; Xs[row][c4 + 3] = v.w;
  }
  {
    const float* wp = Wsrc + (size_t)(kFirst + kk) * 32 * COUT;
    #pragma unroll
    for (int q = 0; q < (8 * COUT) / THREADS; ++q)
      *(float4*)&Ws[(t + q * THREADS) * 4] = *(const float4*)&wp[(t + q * THREADS) * 4];
  }
  __syncthreads();
  constexpr int CG = COUT / 4;
  const int tr = t / CG;                    // 0..15 (row group)
  const int c0 = (t % CG) * 4;
  float acc[8][4];
  #pragma unroll
  for (int u = 0; u < 8; ++u)
    #pragma unroll
    for (int j = 0; j < 4; ++j) acc[u][j] = 0.f;
  #pragma unroll
  for (int i = 0; i < 32; ++i) {
    float4 wv = *(const float4*)&Ws[i * COUT + c0];
    #pragma unroll
    for (int u = 0; u < 8; ++u) {
      float xv = Xs[tr + 16 * u][i];        // rows tr+16u: conflict-free banks
      acc[u][0] = fmaf(xv, wv.x, acc[u][0]);
      acc[u][1] = fmaf(xv, wv.y, acc[u][1]);
      acc[u][2] = fmaf(xv, wv.z, acc[u][2]);
      acc[u][3] = fmaf(xv, wv.w, acc[u][3]);
    }
  }
  #pragma unroll
  for (int u = 0; u < 8; ++u) {
    int row = n0 + tr + 16 * u;
    if (row < N) {
      __half2* yp = (__half2*)(Y + (size_t)row * (size_t)strideY + kk * COUT + c0);
      yp[0] = __floats2half2_rn(acc[u][0], acc[u][1]);
      yp[1] = __floats2half2_rn(acc[u][2], acc[u][3]);
    }
  }
}

// Wave-per-node gather. Quarter q = slot (di0=q&1, di1=q>>1); 16 lanes/quarter
// cover channels. readlane edge-broadcast (uniform), batch-4 loads for MLP.
// fused=1 (single pass): epilogue applies /deg + x@root + bias + relu.
template <int COUT>
__global__ __launch_bounds__(256) void gather_kernel(
    const int2* __restrict__ emeta, const int* __restrict__ offs,
    const __half* __restrict__ Y, int strideY,
    float* __restrict__ hagg, int N, int g0, int g1, int first, int fused,
    const float* __restrict__ X, const float* __restrict__ root,
    const float* __restrict__ bias, float* __restrict__ hout) {
  __shared__ float Rs[32 * COUT];
  const int t = threadIdx.x;
  if (fused) {
    #pragma unroll
    for (int q = 0; q < (8 * COUT) / 256; ++q)
      *(float4*)&Rs[(t + q * 256) * 4] = *(const float4*)&root[(t + q * 256) * 4];
    __syncthreads();
  }
  const int w = t >> 6, lane = t & 63;
  const int n = blockIdx.x * 4 + w;
  if (n >= N) return;
  const int q4 = lane >> 4, r = lane & 15;
  const int di0 = q4 & 1, di1 = q4 >> 1;
  constexpr int CPL = COUT / 16;            // channels per lane: 2 or 4
  const int kBias = di0 + 5 * di1 - 5 * g0;
  const int laneCh = r * CPL;
  float acc[CPL];
  #pragma unroll
  for (int j = 0; j < CPL; ++j) acc[j] = 0.f;
  const int beg = offs[n], end = offs[n + 1];
  for (int b0 = beg; b0 < end; b0 += 64) {
    const int cnt = min(64, end - b0);
    int2 m = emeta[b0 + min(lane, cnt - 1)];
    int myS = m.x, myY = m.y;
    for (int j0 = 0; j0 < cnt; j0 += 4) {
      float wg[4];
      __half2 yv[4][CPL / 2];
      #pragma unroll
      for (int u = 0; u < 4; ++u) {
        int j = j0 + u;
        int jc = (j < cnt) ? j : 0;
        int s  = __builtin_amdgcn_readlane(myS, jc);
        int yw = __builtin_amdgcn_readlane(myY, jc);
        int k0 = yw & 31;
        int i10 = (yw >> 5) & 3;
        float f0 = (float)((yw >> 7) & 4095) * (1.f / 4095.f);
        float f1 = (float)((yw >> 19) & 4095) * (1.f / 4095.f);
        float wt = (di0 ? f0 : 1.f - f0) * (di1 ? f1 : 1.f - f1);
        bool skip = (j >= cnt) || (i10 < g0) || (i10 >= g1);
        wg[u] = skip ? 0.f : wt;
        int rowL = skip ? 0 : (k0 + kBias);
        const __half2* yp =
            (const __half2*)(Y + (size_t)s * (size_t)strideY + rowL * COUT + laneCh);
        #pragma unroll
        for (int p = 0; p < CPL / 2; ++p) yv[u][p] = yp[p];
      }
      #pragma unroll
      for (int u = 0; u < 4; ++u)
        #pragma unroll
        for (int p = 0; p < CPL / 2; ++p) {
          float2 f = __half22float2(yv[u][p]);
          acc[2 * p]     = fmaf(wg[u], f.x, acc[2 * p]);
          acc[2 * p + 1] = fmaf(wg[u], f.y, acc[2 * p + 1]);
        }
    }
  }
  #pragma unroll
  for (int j = 0; j < CPL; ++j) {           // fold the 4 slot-quarters
    acc[j] += __shfl_xor(acc[j], 16);
    acc[j] += __shfl_xor(acc[j], 32);
  }
  if (lane < 16) {
    if (!fused) {
      float* hp = hagg + (size_t)n * COUT + laneCh;
      if constexpr (CPL == 2) {
        float2 o = make_float2(acc[0], acc[1]);
        if (!first) { float2 p = *(float2*)hp; o.x += p.x; o.y += p.y; }
        *(float2*)hp = o;
      } else {
        float4 o = make_float4(acc[0], acc[1], acc[2], acc[3]);
        if (!first) {
          float4 p = *(float4*)hp;
          o.x += p.x; o.y += p.y; o.z += p.z; o.w += p.w;
        }
        *(float4*)hp = o;
      }
    } else {
      float rd = 1.f / (float)max(end - beg, 1);
      float a[CPL];
      #pragma unroll
      for (int j = 0; j < CPL; ++j) a[j] = acc[j] * rd;
      const float* xr = X + (size_t)n * 32;
      for (int i = 0; i < 32; ++i) {
        float xv = xr[i];
        #pragma unroll
        for (int j = 0; j < CPL; ++j)
          a[j] = fmaf(xv, Rs[i * COUT + laneCh + j], a[j]);
      }
      #pragma unroll
      for (int j = 0; j < CPL; ++j) a[j] = fmaxf(a[j] + bias[laneCh + j], 0.f);
      if constexpr (CPL == 2) {
        *(float2*)(hout + (size_t)n * COUT + laneCh) = make_float2(a[0], a[1]);
      } else {
        *(float4*)(hout + (size_t)n * COUT + laneCh) =
            make_float4(a[0], a[1], a[2], a[3]);
      }
    }
  }
}

// Multi-pass fallback: h[n,ch] = relu(agg/deg + x@root + b).
template <int COUT>
__global__ __launch_bounds__(256) void finalize_kernel(
    const float* __restrict__ hagg, const float* __restrict__ X,
    const float* __restrict__ root, const float* __restrict__ bias,
    const int* __restrict__ deg, float* __restrict__ hout, int N) {
  __shared__ float Rs[32 * COUT];
  int t = threadIdx.x;
  #pragma unroll
  for (int q = 0; q < (32 * COUT) / 1024; ++q)
    *(float4*)&Rs[(q * 256 + t) * 4] = *(const float4*)&root[(q * 256 + t) * 4];
  __syncthreads();
  constexpr int TPN = COUT / 4;
  int gid = blockIdx.x * 256 + t;
  int n = gid / TPN;
  int c0 = (gid % TPN) * 4;
  if (n >= N) return;
  const float* xr = X + (size_t)n * 32;
  float rd = 1.f / (float)max(deg[n], 1);
  float4 hv = *(const float4*)&hagg[(size_t)n * COUT + c0];
  float a0 = hv.x * rd, a1 = hv.y * rd, a2 = hv.z * rd, a3 = hv.w * rd;
  #pragma unroll
  for (int i = 0; i < 32; ++i) {
    float xv = xr[i];
    const float* rr = &Rs[i * COUT + c0];
    a0 = fmaf(xv, rr[0], a0);
    a1 = fmaf(xv, rr[1], a1);
    a2 = fmaf(xv, rr[2], a2);
    a3 = fmaf(xv, rr[3], a3);
  }
  float4 o;
  o.x = fmaxf(a0 + bias[c0 + 0], 0.f);
  o.y = fmaxf(a1 + bias[c0 + 1], 0.f);
  o.z = fmaxf(a2 + bias[c0 + 2], 0.f);
  o.w = fmaxf(a3 + bias[c0 + 3], 0.f);
  *(float4*)&hout[(size_t)n * COUT + c0] = o;
}

__global__ __launch_bounds__(256) void pool_kernel(
    const float* __restrict__ h2, const int* __restrict__ batch, int N,
    float* __restrict__ poolacc) {
  __shared__ float red[4][64];
  int g = blockIdx.x >> 2, part = blockIdx.x & 3;
  int lo = lowb(batch, N, g), hi = lowb(batch, N, g + 1);
  int len = hi - lo;
  int b0 = lo + (int)(((long long)len * part) / 4);
  int b1 = lo + (int)(((long long)len * (part + 1)) / 4);
  int r = threadIdx.x >> 6, o = threadIdx.x & 63;
  float s = 0.f;
  for (int row = b0 + r; row < b1; row += 4) s += h2[(size_t)row * 64 + o];
  red[r][o] = s;
  __syncthreads();
  if (r == 0) {
    float v = red[0][o] + red[1][o] + red[2][o] + red[3][o];
    atomicAdd(&poolacc[g * 64 + o], v);
  }
}

__global__ __launch_bounds__(64) void head_kernel(
    const float* __restrict__ poolacc, const int* __restrict__ batch, int N,
    const float* __restrict__ w1, const float* __restrict__ b1,
    const float* __restrict__ w2, const float* __restrict__ b2,
    const float* __restrict__ w3, const float* __restrict__ b3,
    float* __restrict__ out) {
  __shared__ float gb[64];
  __shared__ float lg[10];
  int g = blockIdx.x, o = threadIdx.x;
  int lo = lowb(batch, N, g), hi = lowb(batch, N, g + 1);
  float cnt = fmaxf((float)(hi - lo), 1.f);
  float gv = poolacc[g * 64 + o] / cnt;
  gb[o] = gv;
  __syncthreads();
  float tacc = b1[o];
  for (int i = 0; i < 64; ++i) tacc = fmaf(gb[i], w1[i * 64 + o], tacc);
  gv = gv * (1.f / (1.f + expf(-tacc)));
  __syncthreads(); gb[o] = gv; __syncthreads();
  tacc = b2[o];
  for (int i = 0; i < 64; ++i) tacc = fmaf(gb[i], w2[i * 64 + o], tacc);
  gv = gv * (1.f / (1.f + expf(-tacc)));
  __syncthreads(); gb[o] = gv; __syncthreads();
  if (o < 10) {
    float l = b3[o];
    for (int i = 0; i < 64; ++i) l = fmaf(gb[i], w3[i * 10 + o], l);
    lg[o] = l;
  }
  __syncthreads();
  if (o < 10) {
    float m = lg[0];
    #pragma unroll
    for (int c = 1; c < 10; ++c) m = fmaxf(m, lg[c]);
    float s = 0.f;
    #pragma unroll
    for (int c = 0; c < 10; ++c) s += expf(lg[c] - m);
    out[g * 10 + o] = lg[o] - m - logf(s);
  }
}

extern "C" void kernel_launch(void* const* d_in, const int* in_sizes, int n_in,
                              void* d_out, int out_size, void* d_ws, size_t ws_size,
                              hipStream_t stream) {
  const float* x     = (const float*)d_in[0];
  const int*   ei    = (const int*)d_in[1];
  const float* eattr = (const float*)d_in[2];
  const int*   batch = (const int*)d_in[3];
  const float* W1    = (const float*)d_in[4];
  const float* root1 = (const float*)d_in[5];
  const float* b1    = (const float*)d_in[6];
  const float* W2    = (const float*)d_in[7];
  const float* root2 = (const float*)d_in[8];
  const float* b2    = (const float*)d_in[9];
  const float* l1w   = (const float*)d_in[10];
  const float* l1b   = (const float*)d_in[11];
  const float* l2w   = (const float*)d_in[12];
  const float* l2b   = (const float*)d_in[13];
  const float* l3w   = (const float*)d_in[14];
  const float* l3b   = (const float*)d_in[15];
  float* out = (float*)d_out;

  const int N = in_sizes[0] / 32;
  const int E = in_sizes[1] / 2;
  const int Npad = (N + 63) & ~63;

  char* base = (char*)d_ws;
  size_t off = 0;
  auto walloc = [&](size_t bytes) -> void* {
    off = (off + 255) & ~(size_t)255;
    void* p = base + off;
    off += bytes;
    return p;
  };
  int*   deg     = (int*)walloc((size_t)Npad * 4);
  int*   offs    = (int*)walloc((size_t)(N + 1) * 4);
  int*   cursor  = (int*)walloc((size_t)N * 4);
  int*   bsums   = (int*)walloc(64 * 4);
  int*   boff    = (int*)walloc(64 * 4);
  float* poolacc = (float*)walloc(64 * 64 * 4);
  float* h1      = (float*)walloc((size_t)N * 32 * 4);
  float* h2      = (float*)walloc((size_t)N * 64 * 4);
  int2*  emeta   = (int2*)walloc((size_t)E * 8);
  off = (off + 255) & ~(size_t)255;
  size_t avail = (ws_size > off) ? (ws_size - off) : 0;
  __half* Yb = (__half*)(base + off);

  // i1-group sizing: buffer holds (G+1) row-groups of 5 k-rows each (fp16)
  auto pickG = [&](int cout) -> int {
    size_t g5 = (size_t)N * 5 * cout * 2;
    if (avail < 2 * g5) return 0;
    size_t G = avail / g5 - 1;
    return (int)(G > 4 ? 4 : G);
  };
  int G1 = pickG(32), G2 = pickG(64);
  if (!G1 || !G2) return;                   // insufficient workspace

  const int* srcA = ei;
  const int* dstA = ei + E;

  hipMemsetAsync(deg, 0, (size_t)Npad * 4, stream);
  hipMemsetAsync(cursor, 0, (size_t)N * 4, stream);
  hipMemsetAsync(poolacc, 0, 64 * 64 * 4, stream);

  hist_kernel<<<(E + 255) / 256, 256, 0, stream>>>(dstA, E, deg);
  int nb = (N + 1023) / 1024;
  scan_block_kernel<<<nb, 1024, 0, stream>>>(deg, N, offs, bsums);
  scan_bsums_kernel<<<1, 64, 0, stream>>>(bsums, nb, boff);
  scan_add_kernel<<<(N + 255) / 256, 256, 0, stream>>>(offs, boff, N);
  scatter_kernel<<<(E + 255) / 256, 256, 0, stream>>>(srcA, dstA, (const float2*)eattr,
                                                      E, offs, cursor, emeta);

  const int ygrid = (N + 127) / 128;
  const int ggrid = (N + 3) / 4;
  for (int layer = 0; layer < 2; ++layer) {
    const float* Xin = layer ? h1 : x;
    const float* Wl  = layer ? W2 : W1;
    const float* rl  = layer ? root2 : root1;
    const float* bl  = layer ? b2 : b1;
    float* Hout      = layer ? h2 : h1;
    const int G      = layer ? G2 : G1;
    const int COUT   = layer ? 64 : 32;
    const int fused  = (G >= 4) ? 1 : 0;
    for (int g0 = 0; g0 < 4; g0 += G) {
      int g1 = min(4, g0 + G);
      int kFirst = g0 * 5, kCount = (g1 - g0 + 1) * 5;
      int strideY = kCount * COUT;
      int first = (g0 == 0) ? 1 : 0;
      if (layer == 0) {
        ygemm_kernel<32><<<dim3(ygrid, kCount), 128, 0, stream>>>(
            Xin, Wl, Yb, N, kFirst, strideY);
        gather_kernel<32><<<ggrid, 256, 0, stream>>>(
            emeta, offs, Yb, strideY, Hout, N, g0, g1, first, fused,
            Xin, rl, bl, Hout);
      } else {
        ygemm_kernel<64><<<dim3(ygrid, kCount), 256, 0, stream>>>(
            Xin, Wl, Yb, N, kFirst, strideY);
        gather_kernel<64><<<ggrid, 256, 0, stream>>>(
            emeta, offs, Yb, strideY, Hout, N, g0, g1, first, fused,
            Xin, rl, bl, Hout);
      }
    }
    if (!fused) {
      if (layer == 0)
        finalize_kernel<32><<<((size_t)N * 8 + 255) / 256, 256, 0, stream>>>(
            Hout, Xin, rl, bl, deg, Hout, N);
      else
        finalize_kernel<64><<<((size_t)N * 16 + 255) / 256, 256, 0, stream>>>(
            Hout, Xin, rl, bl, deg, Hout, N);
    }
  }
  pool_kernel<<<256, 256, 0, stream>>>(h2, batch, N, poolacc);
  head_kernel<<<64, 64, 0, stream>>>(poolacc, batch, N,
                                     l1w, l1b, l2w, l2b, l3w, l3b, out);
}

// Round 7
// 500.180 us; speedup vs baseline: 1.3319x; 1.3319x over previous
//
#include <hip/hip_runtime.h>
#include <hip/hip_bf16.h>
#include <hip/hip_fp16.h>
#include <cstdint>

// ---------------------------------------------------------------------------
// SplineNet forward on gfx950 — gather formulation, fp16 conv chain.
//   x2h/w2h: one-time fp16 conversions (X, W transposed to [col][k])
//   mfma_ygemm: Y[n, k*Cout+ch] = X[n] @ W[k] via v_mfma_f32_16x16x32_f16
//               (K=32 in ONE mfma; 4 waves x 4 col-tiles; LDS-staged stores)
//   gather: agg[n,ch] = sum_e sum_s basis_s(e) * Y[src_e, k_s, ch]
//           wave-per-node; quarter=slot; readlane broadcast; fused finalize
//   pool/head: graph mean-pool + gated MLP + log_softmax
// ---------------------------------------------------------------------------

typedef _Float16 half8 __attribute__((ext_vector_type(8)));
typedef float f32x4 __attribute__((ext_vector_type(4)));

__device__ __forceinline__ int lowb(const int* __restrict__ a, int n, int v) {
  int lo = 0, hi = n;
  while (lo < hi) { int m = (lo + hi) >> 1; if (a[m] < v) lo = m + 1; else hi = m; }
  return lo;
}

__global__ void hist_kernel(const int* __restrict__ dst, int E, int* __restrict__ deg) {
  int e = blockIdx.x * 256 + threadIdx.x;
  if (e < E) atomicAdd(&deg[dst[e]], 1);
}

__global__ __launch_bounds__(1024) void scan_block_kernel(
    const int* __restrict__ deg, int n, int* __restrict__ offs, int* __restrict__ bsums) {
  __shared__ int wsum[16];
  int t = threadIdx.x;
  int gi = blockIdx.x * 1024 + t;
  int v = (gi < n) ? deg[gi] : 0;
  int lane = t & 63, w = t >> 6;
  int x = v;
  #pragma unroll
  for (int d = 1; d < 64; d <<= 1) { int y = __shfl_up(x, d, 64); if (lane >= d) x += y; }
  if (lane == 63) wsum[w] = x;
  __syncthreads();
  if (w == 0) {
    int s = (lane < 16) ? wsum[lane] : 0;
    #pragma unroll
    for (int d = 1; d < 16; d <<= 1) { int y = __shfl_up(s, d, 64); if (lane >= d) s += y; }
    if (lane < 16) wsum[lane] = s;
  }
  __syncthreads();
  int add = (w > 0) ? wsum[w - 1] : 0;
  x += add;
  if (gi < n) offs[gi + 1] = x;
  if (t == 1023) bsums[blockIdx.x] = x;
}

__global__ __launch_bounds__(64) void scan_bsums_kernel(
    const int* __restrict__ bsums, int nb, int* __restrict__ boff) {
  int l = threadIdx.x;
  int v = (l < nb) ? bsums[l] : 0;
  int x = v;
  #pragma unroll
  for (int d = 1; d < 64; d <<= 1) { int y = __shfl_up(x, d, 64); if (l >= d) x += y; }
  if (l < nb) boff[l] = x - v;
}

__global__ void scan_add_kernel(int* __restrict__ offs, const int* __restrict__ boff, int n) {
  int i = blockIdx.x * 256 + threadIdx.x;
  if (i < n) offs[i + 1] += boff[i >> 10];
  if (i == 0) offs[0] = 0;
}

// CSR scatter + packed spline metadata {src, k0|i10<<5|f0q<<7|f1q<<19}.
__global__ void scatter_kernel(const int* __restrict__ src, const int* __restrict__ dst,
                               const float2* __restrict__ attr, int E,
                               const int* __restrict__ offs, int* __restrict__ cursor,
                               int2* __restrict__ emeta) {
  int e = blockIdx.x * 256 + threadIdx.x;
  if (e < E) {
    float2 a = attr[e];
    float v0 = a.x * 4.f, v1 = a.y * 4.f;
    int i00 = min((int)v0, 3);
    int i10 = min((int)v1, 3);
    float f0 = v0 - (float)i00;             // clamp trick: boundary exact
    float f1 = v1 - (float)i10;
    int f0q = (int)(f0 * 4095.f + 0.5f);
    int f1q = (int)(f1 * 4095.f + 0.5f);
    int yw = (i10 * 5 + i00) | (i10 << 5) | (f0q << 7) | (f1q << 19);
    int d = dst[e];
    int p = offs[d] + atomicAdd(&cursor[d], 1);
    emeta[p] = make_int2(src[e], yw);
  }
}

__global__ void x2h_kernel(const float* __restrict__ X, __half* __restrict__ Xh, int n) {
  int i = blockIdx.x * 256 + threadIdx.x;
  if (i < n) Xh[i] = __float2half(X[i]);
}

// Wh[(kk*COUT+ch)*32 + i] = W[(kk*32+i)*COUT + ch]
__global__ void w2h_kernel(const float* __restrict__ W, __half* __restrict__ Wh,
                           int ncolTot, int COUT) {
  int idx = blockIdx.x * 256 + threadIdx.x;
  if (idx < ncolTot * 32) {
    int col = idx >> 5, i = idx & 31;
    int kk = col / COUT, ch = col - kk * COUT;
    Wh[idx] = __float2half(W[(kk * 32 + i) * COUT + ch]);
  }
}

// MFMA ygemm: block = 4 waves on one 16-row stripe; wave w covers col-tiles
// [blockIdx.y*256 + w*64 .. +64). A frag: m=lane&15, k=(lane>>4)*8+j.
// B frag: n=lane&15 (col), k=(lane>>4)*8+j from Wh[col][k]. D: col=lane&15,
// row=(lane>>4)*4+r (HW-verified). LDS-staged, coalesced 32B/thread stores.
__global__ __launch_bounds__(256) void mfma_ygemm(
    const __half* __restrict__ Xh, const __half* __restrict__ Wh,
    __half* __restrict__ Y, int N, int ncol, int strideY) {
  __shared__ __half Ls[16 * 264];           // row stride 264 (pad) halfs
  const int t = threadIdx.x;
  const int w = t >> 6, lane = t & 63;
  const int rowBase = blockIdx.x * 16;
  const int colBase = blockIdx.y * 256;
  const int kOff = (lane >> 4) * 8;
  int arow = min(rowBase + (lane & 15), N - 1);
  const half8 Af = *(const half8*)(Xh + (size_t)arow * 32 + kOff);
  half8 Bf[4];
  #pragma unroll
  for (int c = 0; c < 4; ++c) {
    int col = min(colBase + w * 64 + c * 16 + (lane & 15), ncol - 1);
    Bf[c] = *(const half8*)(Wh + (size_t)col * 32 + kOff);
  }
  f32x4 zero = {0.f, 0.f, 0.f, 0.f};
  f32x4 acc[4];
  #pragma unroll
  for (int c = 0; c < 4; ++c)
    acc[c] = __builtin_amdgcn_mfma_f32_16x16x32_f16(Af, Bf[c], zero, 0, 0, 0);
  #pragma unroll
  for (int c = 0; c < 4; ++c) {
    int col = w * 64 + c * 16 + (lane & 15);
    int r0 = (lane >> 4) * 4;
    #pragma unroll
    for (int r = 0; r < 4; ++r)
      Ls[(r0 + r) * 264 + col] = __float2half(acc[c][r]);
  }
  __syncthreads();
  int row = rowBase + (t >> 4);
  int cseg = (t & 15) * 16;                 // 16 halfs = 32 B per thread
  if (row < N && colBase + cseg < ncol) {
    int4* dst = (int4*)(Y + (size_t)row * (size_t)strideY + colBase + cseg);
    const int4* srcp = (const int4*)(Ls + (t >> 4) * 264 + cseg);
    dst[0] = srcp[0];
    dst[1] = srcp[1];
  }
}

// Wave-per-node gather. Quarter q = slot (di0=q&1, di1=q>>1); 16 lanes/quarter
// cover channels. readlane edge-broadcast, batch-4 loads for MLP.
// fused=1: epilogue applies /deg + x@root + bias + relu, writes fp16 h.
template <int COUT>
__global__ __launch_bounds__(256) void gather_kernel(
    const int2* __restrict__ emeta, const int* __restrict__ offs,
    const __half* __restrict__ Y, int strideY,
    float* __restrict__ hagg, int N, int g0, int g1, int first, int fused,
    const __half* __restrict__ X, const float* __restrict__ root,
    const float* __restrict__ bias, __half* __restrict__ hout) {
  __shared__ float Rs[32 * COUT];
  const int t = threadIdx.x;
  if (fused) {
    #pragma unroll
    for (int q = 0; q < (8 * COUT) / 256; ++q)
      *(float4*)&Rs[(t + q * 256) * 4] = *(const float4*)&root[(t + q * 256) * 4];
    __syncthreads();
  }
  const int w = t >> 6, lane = t & 63;
  const int n = blockIdx.x * 4 + w;
  if (n >= N) return;
  const int q4 = lane >> 4, r = lane & 15;
  const int di0 = q4 & 1, di1 = q4 >> 1;
  constexpr int CPL = COUT / 16;            // channels per lane: 2 or 4
  const int kBias = di0 + 5 * di1 - 5 * g0;
  const int laneCh = r * CPL;
  float acc[CPL];
  #pragma unroll
  for (int j = 0; j < CPL; ++j) acc[j] = 0.f;
  const int beg = offs[n], end = offs[n + 1];
  for (int b0 = beg; b0 < end; b0 += 64) {
    const int cnt = min(64, end - b0);
    int2 m = emeta[b0 + min(lane, cnt - 1)];
    int myS = m.x, myY = m.y;
    for (int j0 = 0; j0 < cnt; j0 += 4) {
      float wg[4];
      __half2 yv[4][CPL / 2];
      #pragma unroll
      for (int u = 0; u < 4; ++u) {
        int j = j0 + u;
        int jc = (j < cnt) ? j : 0;
        int s  = __builtin_amdgcn_readlane(myS, jc);
        int yw = __builtin_amdgcn_readlane(myY, jc);
        int k0 = yw & 31;
        int i10 = (yw >> 5) & 3;
        float f0 = (float)((yw >> 7) & 4095) * (1.f / 4095.f);
        float f1 = (float)((yw >> 19) & 4095) * (1.f / 4095.f);
        float wt = (di0 ? f0 : 1.f - f0) * (di1 ? f1 : 1.f - f1);
        bool skip = (j >= cnt) || (i10 < g0) || (i10 >= g1);
        wg[u] = skip ? 0.f : wt;
        int rowL = skip ? 0 : (k0 + kBias);
        const __half2* yp =
            (const __half2*)(Y + (size_t)s * (size_t)strideY + rowL * COUT + laneCh);
        #pragma unroll
        for (int p = 0; p < CPL / 2; ++p) yv[u][p] = yp[p];
      }
      #pragma unroll
      for (int u = 0; u < 4; ++u)
        #pragma unroll
        for (int p = 0; p < CPL / 2; ++p) {
          float2 f = __half22float2(yv[u][p]);
          acc[2 * p]     = fmaf(wg[u], f.x, acc[2 * p]);
          acc[2 * p + 1] = fmaf(wg[u], f.y, acc[2 * p + 1]);
        }
    }
  }
  #pragma unroll
  for (int j = 0; j < CPL; ++j) {           // fold the 4 slot-quarters
    acc[j] += __shfl_xor(acc[j], 16);
    acc[j] += __shfl_xor(acc[j], 32);
  }
  if (lane < 16) {
    if (!fused) {
      float* hp = hagg + (size_t)n * COUT + laneCh;
      if constexpr (CPL == 2) {
        float2 o = make_float2(acc[0], acc[1]);
        if (!first) { float2 p = *(float2*)hp; o.x += p.x; o.y += p.y; }
        *(float2*)hp = o;
      } else {
        float4 o = make_float4(acc[0], acc[1], acc[2], acc[3]);
        if (!first) {
          float4 p = *(float4*)hp;
          o.x += p.x; o.y += p.y; o.z += p.z; o.w += p.w;
        }
        *(float4*)hp = o;
      }
    } else {
      float rd = 1.f / (float)max(end - beg, 1);
      float a[CPL];
      #pragma unroll
      for (int j = 0; j < CPL; ++j) a[j] = acc[j] * rd;
      const __half* xr = X + (size_t)n * 32;
      for (int i = 0; i < 32; ++i) {
        float xv = __half2float(xr[i]);
        #pragma unroll
        for (int j = 0; j < CPL; ++j)
          a[j] = fmaf(xv, Rs[i * COUT + laneCh + j], a[j]);
      }
      #pragma unroll
      for (int j = 0; j < CPL; ++j) a[j] = fmaxf(a[j] + bias[laneCh + j], 0.f);
      __half2* op = (__half2*)(hout + (size_t)n * COUT + laneCh);
      #pragma unroll
      for (int p = 0; p < CPL / 2; ++p)
        op[p] = __floats2half2_rn(a[2 * p], a[2 * p + 1]);
    }
  }
}

// Multi-pass fallback: h[n,ch] = relu(agg/deg + x@root + b) -> fp16.
template <int COUT>
__global__ __launch_bounds__(256) void finalize_kernel(
    const float* __restrict__ hagg, const __half* __restrict__ X,
    const float* __restrict__ root, const float* __restrict__ bias,
    const int* __restrict__ deg, __half* __restrict__ hout, int N) {
  __shared__ float Rs[32 * COUT];
  int t = threadIdx.x;
  #pragma unroll
  for (int q = 0; q < (32 * COUT) / 1024; ++q)
    *(float4*)&Rs[(q * 256 + t) * 4] = *(const float4*)&root[(q * 256 + t) * 4];
  __syncthreads();
  constexpr int TPN = COUT / 4;
  int gid = blockIdx.x * 256 + t;
  int n = gid / TPN;
  int c0 = (gid % TPN) * 4;
  if (n >= N) return;
  const __half* xr = X + (size_t)n * 32;
  float rd = 1.f / (float)max(deg[n], 1);
  float4 hv = *(const float4*)&hagg[(size_t)n * COUT + c0];
  float a0 = hv.x * rd, a1 = hv.y * rd, a2 = hv.z * rd, a3 = hv.w * rd;
  #pragma unroll
  for (int i = 0; i < 32; ++i) {
    float xv = __half2float(xr[i]);
    const float* rr = &Rs[i * COUT + c0];
    a0 = fmaf(xv, rr[0], a0);
    a1 = fmaf(xv, rr[1], a1);
    a2 = fmaf(xv, rr[2], a2);
    a3 = fmaf(xv, rr[3], a3);
  }
  __half2* op = (__half2*)(hout + (size_t)n * COUT + c0);
  op[0] = __floats2half2_rn(fmaxf(a0 + bias[c0 + 0], 0.f),
                            fmaxf(a1 + bias[c0 + 1], 0.f));
  op[1] = __floats2half2_rn(fmaxf(a2 + bias[c0 + 2], 0.f),
                            fmaxf(a3 + bias[c0 + 3], 0.f));
}

__global__ __launch_bounds__(256) void pool_kernel(
    const __half* __restrict__ h2, const int* __restrict__ batch, int N,
    float* __restrict__ poolacc) {
  __shared__ float red[4][64];
  int g = blockIdx.x >> 2, part = blockIdx.x & 3;
  int lo = lowb(batch, N, g), hi = lowb(batch, N, g + 1);
  int len = hi - lo;
  int b0 = lo + (int)(((long long)len * part) / 4);
  int b1 = lo + (int)(((long long)len * (part + 1)) / 4);
  int r = threadIdx.x >> 6, o = threadIdx.x & 63;
  float s = 0.f;
  for (int row = b0 + r; row < b1; row += 4)
    s += __half2float(h2[(size_t)row * 64 + o]);
  red[r][o] = s;
  __syncthreads();
  if (r == 0) {
    float v = red[0][o] + red[1][o] + red[2][o] + red[3][o];
    atomicAdd(&poolacc[g * 64 + o], v);
  }
}

__global__ __launch_bounds__(64) void head_kernel(
    const float* __restrict__ poolacc, const int* __restrict__ batch, int N,
    const float* __restrict__ w1, const float* __restrict__ b1,
    const float* __restrict__ w2, const float* __restrict__ b2,
    const float* __restrict__ w3, const float* __restrict__ b3,
    float* __restrict__ out) {
  __shared__ float gb[64];
  __shared__ float lg[10];
  int g = blockIdx.x, o = threadIdx.x;
  int lo = lowb(batch, N, g), hi = lowb(batch, N, g + 1);
  float cnt = fmaxf((float)(hi - lo), 1.f);
  float gv = poolacc[g * 64 + o] / cnt;
  gb[o] = gv;
  __syncthreads();
  float tacc = b1[o];
  for (int i = 0; i < 64; ++i) tacc = fmaf(gb[i], w1[i * 64 + o], tacc);
  gv = gv * (1.f / (1.f + expf(-tacc)));
  __syncthreads(); gb[o] = gv; __syncthreads();
  tacc = b2[o];
  for (int i = 0; i < 64; ++i) tacc = fmaf(gb[i], w2[i * 64 + o], tacc);
  gv = gv * (1.f / (1.f + expf(-tacc)));
  __syncthreads(); gb[o] = gv; __syncthreads();
  if (o < 10) {
    float l = b3[o];
    for (int i = 0; i < 64; ++i) l = fmaf(gb[i], w3[i * 10 + o], l);
    lg[o] = l;
  }
  __syncthreads();
  if (o < 10) {
    float m = lg[0];
    #pragma unroll
    for (int c = 1; c < 10; ++c) m = fmaxf(m, lg[c]);
    float s = 0.f;
    #pragma unroll
    for (int c = 0; c < 10; ++c) s += expf(lg[c] - m);
    out[g * 10 + o] = lg[o] - m - logf(s);
  }
}

extern "C" void kernel_launch(void* const* d_in, const int* in_sizes, int n_in,
                              void* d_out, int out_size, void* d_ws, size_t ws_size,
                              hipStream_t stream) {
  const float* x     = (const float*)d_in[0];
  const int*   ei    = (const int*)d_in[1];
  const float* eattr = (const float*)d_in[2];
  const int*   batch = (const int*)d_in[3];
  const float* W1    = (const float*)d_in[4];
  const float* root1 = (const float*)d_in[5];
  const float* b1    = (const float*)d_in[6];
  const float* W2    = (const float*)d_in[7];
  const float* root2 = (const float*)d_in[8];
  const float* b2    = (const float*)d_in[9];
  const float* l1w   = (const float*)d_in[10];
  const float* l1b   = (const float*)d_in[11];
  const float* l2w   = (const float*)d_in[12];
  const float* l2b   = (const float*)d_in[13];
  const float* l3w   = (const float*)d_in[14];
  const float* l3b   = (const float*)d_in[15];
  float* out = (float*)d_out;

  const int N = in_sizes[0] / 32;
  const int E = in_sizes[1] / 2;
  const int Npad = (N + 63) & ~63;

  char* base = (char*)d_ws;
  size_t off = 0;
  auto walloc = [&](size_t bytes) -> void* {
    off = (off + 255) & ~(size_t)255;
    void* p = base + off;
    off += bytes;
    return p;
  };
  int*    deg     = (int*)walloc((size_t)Npad * 4);
  int*    offs    = (int*)walloc((size_t)(N + 1) * 4);
  int*    cursor  = (int*)walloc((size_t)N * 4);
  int*    bsums   = (int*)walloc(64 * 4);
  int*    boff    = (int*)walloc(64 * 4);
  float*  poolacc = (float*)walloc(64 * 64 * 4);
  __half* h1h     = (__half*)walloc((size_t)N * 32 * 2);
  __half* h2h     = (__half*)walloc((size_t)N * 64 * 2);
  __half* Xh      = (__half*)walloc((size_t)N * 32 * 2);
  __half* Wh1     = (__half*)walloc((size_t)800 * 32 * 2);
  __half* Wh2     = (__half*)walloc((size_t)1600 * 32 * 2);
  float*  hagg    = (float*)walloc((size_t)N * 64 * 4);
  int2*   emeta   = (int2*)walloc((size_t)E * 8);
  off = (off + 255) & ~(size_t)255;
  size_t avail = (ws_size > off) ? (ws_size - off) : 0;
  __half* Yb = (__half*)(base + off);

  auto pickG = [&](int cout) -> int {
    size_t g5 = (size_t)N * 5 * cout * 2;
    if (avail < 2 * g5) return 0;
    size_t G = avail / g5 - 1;
    return (int)(G > 4 ? 4 : G);
  };
  int G1 = pickG(32), G2 = pickG(64);
  if (!G1 || !G2) return;                   // insufficient workspace

  const int* srcA = ei;
  const int* dstA = ei + E;

  hipMemsetAsync(deg, 0, (size_t)Npad * 4, stream);
  hipMemsetAsync(cursor, 0, (size_t)N * 4, stream);
  hipMemsetAsync(poolacc, 0, 64 * 64 * 4, stream);

  hist_kernel<<<(E + 255) / 256, 256, 0, stream>>>(dstA, E, deg);
  int nb = (N + 1023) / 1024;
  scan_block_kernel<<<nb, 1024, 0, stream>>>(deg, N, offs, bsums);
  scan_bsums_kernel<<<1, 64, 0, stream>>>(bsums, nb, boff);
  scan_add_kernel<<<(N + 255) / 256, 256, 0, stream>>>(offs, boff, N);
  scatter_kernel<<<(E + 255) / 256, 256, 0, stream>>>(srcA, dstA, (const float2*)eattr,
                                                      E, offs, cursor, emeta);
  x2h_kernel<<<((size_t)N * 32 + 255) / 256, 256, 0, stream>>>(x, Xh, N * 32);
  w2h_kernel<<<(800 * 32 + 255) / 256, 256, 0, stream>>>(W1, Wh1, 800, 32);
  w2h_kernel<<<(1600 * 32 + 255) / 256, 256, 0, stream>>>(W2, Wh2, 1600, 64);

  const int rowTiles = (N + 15) / 16;
  const int ggrid = (N + 3) / 4;
  for (int layer = 0; layer < 2; ++layer) {
    const __half* XinH = layer ? h1h : Xh;
    const __half* WhL  = layer ? Wh2 : Wh1;
    const float* rl    = layer ? root2 : root1;
    const float* bl    = layer ? b2 : b1;
    __half* HoutH      = layer ? h2h : h1h;
    const int G        = layer ? G2 : G1;
    const int COUT     = layer ? 64 : 32;
    const int fused    = (G >= 4) ? 1 : 0;
    for (int g0 = 0; g0 < 4; g0 += G) {
      int g1 = min(4, g0 + G);
      int kFirst = g0 * 5, kCount = (g1 - g0 + 1) * 5;
      int ncol = kCount * COUT;
      int first = (g0 == 0) ? 1 : 0;
      dim3 yg(rowTiles, (ncol + 255) / 256);
      mfma_ygemm<<<yg, 256, 0, stream>>>(XinH, WhL + (size_t)(kFirst * COUT) * 32,
                                         Yb, N, ncol, ncol);
      if (layer == 0)
        gather_kernel<32><<<ggrid, 256, 0, stream>>>(
            emeta, offs, Yb, ncol, hagg, N, g0, g1, first, fused,
            XinH, rl, bl, HoutH);
      else
        gather_kernel<64><<<ggrid, 256, 0, stream>>>(
            emeta, offs, Yb, ncol, hagg, N, g0, g1, first, fused,
            XinH, rl, bl, HoutH);
    }
    if (!fused) {
      if (layer == 0)
        finalize_kernel<32><<<((size_t)N * 8 + 255) / 256, 256, 0, stream>>>(
            hagg, XinH, rl, bl, deg, HoutH, N);
      else
        finalize_kernel<64><<<((size_t)N * 16 + 255) / 256, 256, 0, stream>>>(
            hagg, XinH, rl, bl, deg, HoutH, N);
    }
  }
  pool_kernel<<<256, 256, 0, stream>>>(h2h, batch, N, poolacc);
  head_kernel<<<64, 64, 0, stream>>>(poolacc, batch, N,
                                     l1w, l1b, l2w, l2b, l3w, l3b, out);
}